// Round 17
// baseline (169.431 us; speedup 1.0000x reference)
//
#include <hip/hip_runtime.h>

typedef short short8 __attribute__((ext_vector_type(8)));
typedef float floatx4 __attribute__((ext_vector_type(4)));

#define VOL 41472   // 6*24*24*12
#define EPSV 1e-5f
#define SLOPE 0.1f

// Padded act half-tensors (stride 16 ch): pv(t,x,y,z) = ((t*24+x)*28+y+2)*16+z+2
// half h at ACT + h*HALFELEMS. Halo rows (py 0,1,26,27 / pz 0,1,14,15) zero.
#define HALFBYTES 2064384u
#define HALFELEMS 1032192u
#define ACT_B     256u
#define CONVB_B   4129280u                 // bf16 conv out VOL*32*2 = 2,654,208
#define WB_B      6783488u                 // 120000 short8 = 1.92MB
#define PART_B    8703488u                 // 1152*32*2*4 = 294,912
#define STATS_B   8998400u                 // 512B

__device__ inline unsigned short f2bf(float f) {
  unsigned u = __builtin_bit_cast(unsigned, f);
  unsigned r = u + 0x7fffu + ((u >> 16) & 1u);
  return (unsigned short)(r >> 16);
}
__device__ inline float bf2f(unsigned short h) {
  unsigned u = ((unsigned)h) << 16;
  return __builtin_bit_cast(float, u);
}

// ---------------- init: halo-zero + embed + wtrans (one kernel) ------------
__global__ __launch_bounds__(256) void init_all(
    const float* __restrict__ x, const float* __restrict__ w_emb,
    const float* __restrict__ b_emb, const float* __restrict__ w1,
    const float* __restrict__ w2, const float* __restrict__ w3,
    unsigned short* __restrict__ act, short8* __restrict__ wb) {
  const int bid = blockIdx.x;
  if (bid < 180) {
    int id = bid * 256 + threadIdx.x;
    if (id < 46080) {
      int half = id / 23040;
      int r0 = id % 23040;
      int colm = r0 / 160;                  // t*24+x
      int r = r0 % 160;
      int py, pz;
      if (r < 64) { int sel = r >> 4; py = (sel < 2) ? sel : sel + 24; pz = r & 15; }
      else { int rr = r - 64; py = 2 + (rr >> 2); int s = rr & 3; pz = (s < 2) ? s : s + 12; }
      size_t pv = ((size_t)colm * 28 + py) * 16 + pz;
      short8 zz = {0,0,0,0,0,0,0,0};
      short8* p = reinterpret_cast<short8*>(act + (size_t)half * HALFELEMS + pv * 16);
      p[0] = zz; p[1] = zz;
    }
  } else if (bid < 342) {
    int v = (bid - 180) * 256 + threadIdx.x;
    const float4* xp = reinterpret_cast<const float4*>(x + (size_t)v * 8);
    float4 x0 = xp[0], x1 = xp[1];
    float xv[8] = {x0.x, x0.y, x0.z, x0.w, x1.x, x1.y, x1.z, x1.w};
    float acc[16];
    #pragma unroll
    for (int h = 0; h < 16; ++h) acc[h] = b_emb[h];
    #pragma unroll
    for (int f = 0; f < 8; ++f)
      #pragma unroll
      for (int h = 0; h < 16; ++h)
        acc[h] = fmaf(xv[f], w_emb[f * 16 + h], acc[h]);
    int z = v % 12, y = (v / 12) % 24, xx = (v / 288) % 24, t = v / 6912;
    size_t pa = ((size_t)((t * 24 + xx) * 28 + y + 2) * 16 + z + 2) * 16;
    short8 o0, o1;
    #pragma unroll
    for (int h = 0; h < 8; ++h) { o0[h] = (short)f2bf(acc[h]); o1[h] = (short)f2bf(acc[8 + h]); }
    short8* op = reinterpret_cast<short8*>(act + pa);
    op[0] = o0; op[1] = o1;
  } else {
    int id = (bid - 342) * 256 + threadIdx.x;
    if (id >= 120000) return;
    int lane = id & 63;
    int n = lane & 15, g = lane >> 4;
    int dzb = g >> 1, cib = (g & 1) * 8;
    short8 out;
    if (id < 24000) {
      int q6 = id >> 6;
      int p = q6 % 3, q = q6 / 3;
      int dz = 2 * p + dzb;
      #pragma unroll
      for (int j = 0; j < 8; ++j)
        out[j] = (short)((dz < 5) ? f2bf(w1[((size_t)n * 16 + cib + j) * 625 + q * 5 + dz]) : 0);
    } else if (id < 72000) {
      int q6 = (id - 24000) >> 6;
      int cg = q6 & 1, p = (q6 >> 1) % 3, q = q6 / 6;
      int dz = 2 * p + dzb;
      int co = cg * 16 + n;
      #pragma unroll
      for (int j = 0; j < 8; ++j)
        out[j] = (short)((dz < 5) ? f2bf(w2[((size_t)co * 16 + cib + j) * 625 + q * 5 + dz]) : 0);
    } else {
      int q6 = (id - 72000) >> 6;
      int p = q6 % 3, Q = q6 / 3;
      int h = Q & 1, q125 = Q >> 1;
      int dz = 2 * p + dzb;
      #pragma unroll
      for (int j = 0; j < 8; ++j)
        out[j] = (short)((dz < 5) ? f2bf(w3[((size_t)n * 32 + h * 16 + cib + j) * 625 + q125 * 5 + dz]) : 0);
    }
    wb[id] = out;
  }
}

// ---------------- conv4d v17: v15 core, 256-thr blocks (KSB=2) ------------
// 576 blocks (t,x,yq=6rows) x 4 waves (2 y-triples x 2 vtap-slices), 256 thr.
// v13-v16 pinned at Occupancy ~26% (8-wave 42-50KB blocks -> ~2/CU); nothing
// else saturated. Halving block size -> 21-25KB LDS -> 6-7 blocks/CU =
// 24-28 waves/CU so cross-block waves hide barrier drains + L2 latency.
// Core unchanged: 32B-stride dbuf slabs, 1 barrier/step, no swizzle.
// Guard rows 0,1 + slack rows 162..164 zeroed (NaN*0 = NaN, R11 lesson).
template<int NH, int NCOG>
__global__ __launch_bounds__(256, 4) void conv4d_v17(
    const unsigned short* __restrict__ act, const short8* __restrict__ wb,
    const float* __restrict__ bias, unsigned short* __restrict__ convout,
    float* __restrict__ part) {
  constexpr int COUT = NCOG * 16;
  constexpr int BUFSZ = 165 * 32;               // 2 guard + 160 data + 3 slack
  constexpr int DYST = NH * 3 * NCOG * 64;      // short8 units per dy step
  constexpr int OVER = 4 * 3 * NCOG * 64 * 16;  // epilogue overlay bytes
  constexpr int SLAB4 = 4 * BUFSZ;              // 21120
  constexpr int LDSZ = (OVER > SLAB4) ? OVER : SLAB4;

  __shared__ __align__(16) char lds[LDSZ];
  __shared__ int vlist[52];

  const int tid = threadIdx.x;
  const int l = tid & 63;
  const int w = tid >> 6;                      // wave 0..3
  const int ks = w & 1;                        // vtap slice (2)
  const int yt = w >> 1;                       // y-triple (2)
  const int col = l & 15, g = l >> 4;
  const int bid = blockIdx.x;                  // no swizzle (R14 lesson)
  const int yq = bid & 3;
  const int x = (bid >> 2) % 24;
  const int t = bid / 96;
  const int y0q = yq * 6;

  // zero guard rows {0,1} + slack rows {162,163,164} of all 4 buffers
  for (int i = tid; i < 160; i += 256) {
    int b = i / 40, j = i % 40;
    int row = (j < 16) ? (j >> 3) : (162 + ((j - 16) >> 3));
    ((int*)(lds + b * BUFSZ + row * 32))[j & 7] = 0;
  }
  // wave-parallel vlist build (wave 0)
  if (tid < 64) {
    int q = tid;
    bool val = false; int pi = 0;
    if (q < 25) {
      int ti = t + q / 5 - 2, xi = x + q % 5 - 2;
      val = ((unsigned)ti < 6u) && ((unsigned)xi < 24u);
      pi = ti * 24 + xi;
    }
    unsigned long long mask = __ballot(val);
    int pos = __popcll(mask & ((1ull << tid) - 1ull));
    if (val)
      #pragma unroll
      for (int h = 0; h < NH; ++h)
        vlist[pos * NH + h] = (pi << 16) | (q * 5 * NH + h);
    if (tid == 0) vlist[51] = __popcll(mask) * NH;
  }
  __syncthreads();
  const int nv = vlist[51];
  const int lo = (nv * ks) >> 1;
  const int hi = (nv * (ks + 1)) >> 1;
  const int nsteps = (nv + 1) >> 1;

  char* const buf0 = lds + (ks * 2) * BUFSZ;
  char* const buf1 = buf0 + BUFSZ;
  const int sid = yt * 64 + l;                 // staging id 0..127 per slice
  const bool r2v = (sid < 64);                 // chunk sid+256 < 320
  const char* const abase = (const char*)act;

  // A-frag read bases (2-row guard cancels the pz -2 halo offset)
  const char* const arp0 = buf0 + (yt * 48 + col + (g >> 1)) * 32 + (g & 1) * 16;
  const char* const arp1 = buf1 + (yt * 48 + col + (g >> 1)) * 32 + (g & 1) * 16;

  floatx4 acc[3][NCOG];
  #pragma unroll
  for (int m = 0; m < 3; ++m)
    #pragma unroll
    for (int cg = 0; cg < NCOG; ++cg) acc[m][cg] = (floatx4){0.f, 0.f, 0.f, 0.f};

  short8 R[3];
  // staging: 320 chunks of 16B, contiguous src AND dst (conflict-free)
  #define STAGE_LOAD(vt) do {                                                  \
    int e_ = vlist[vt];                                                        \
    int pi_ = e_ >> 16, h_ = (NH == 2) ? (e_ & 1) : 0;                         \
    const char* s_ = abase + (size_t)h_ * HALFBYTES +                          \
        ((size_t)(pi_ * 28 + y0q) * 16) * 32 + sid * 16;                       \
    R[0] = *(const short8*)(s_);                                               \
    R[1] = *(const short8*)(s_ + 2048);                                        \
    if (r2v) R[2] = *(const short8*)(s_ + 4096);                               \
  } while (0)
  #define STAGE_WRITE(b_) do {                                                 \
    char* d_ = (b_) + 64 + sid * 16;                                           \
    *(short8*)(d_) = R[0];                                                     \
    *(short8*)(d_ + 2048) = R[1];                                              \
    if (r2v) *(short8*)(d_ + 4096) = R[2];                                     \
  } while (0)

  if (lo < hi) { STAGE_LOAD(lo); STAGE_WRITE(buf0); }
  if (lo + 1 < hi) STAGE_LOAD(lo + 1);

  for (int s = 0; s < nsteps; ++s) {
    __syncthreads();                           // buf[s&1] staged, prior reads done
    if (lo + s + 1 < hi) STAGE_WRITE((s & 1) ? buf0 : buf1);  // R holds s+1
    if (lo + s + 2 < hi) STAGE_LOAD(lo + s + 2);              // prefetch s+2
    if (lo + s < hi) {                         // compute vtap s from buf[s&1]
      const int e = vlist[lo + s];
      const short8* bp = wb + (size_t)(e & 0xFFFF) * (3 * NCOG * 64) + l;
      const char* arp = (s & 1) ? arp1 : arp0;
      short8 W[3][3];
      #pragma unroll
      for (int r = 0; r < 3; ++r)
        #pragma unroll
        for (int p = 0; p < 3; ++p)
          W[r][p] = *(const short8*)(arp + r * 512 + p * 64);
      #pragma unroll
      for (int dy = 0; dy < 5; ++dy) {
        short8 Bf[3][NCOG];
        #pragma unroll
        for (int p = 0; p < 3; ++p)
          #pragma unroll
          for (int cg = 0; cg < NCOG; ++cg)
            Bf[p][cg] = bp[dy * DYST + (p * NCOG + cg) * 64];
        #pragma unroll
        for (int p = 0; p < 3; ++p)
          #pragma unroll
          for (int cg = 0; cg < NCOG; ++cg)
            #pragma unroll
            for (int m = 0; m < 3; ++m)
              acc[m][cg] = __builtin_amdgcn_mfma_f32_16x16x32_bf16(
                  W[(dy + m) % 3][p], Bf[p][cg], acc[m][cg], 0, 0, 0);
        if (dy < 4) {
          #pragma unroll
          for (int p = 0; p < 3; ++p)
            W[dy % 3][p] = *(const short8*)(arp + (dy + 3) * 512 + p * 64);
        }
      }
    }
  }
  #undef STAGE_LOAD
  #undef STAGE_WRITE

  // ---- epilogue: overlay reduce over 2 slices, bias, bf16, BN partials ----
  float4* redf = (float4*)lds;
  __syncthreads();                             // all waves done with slabs
  #pragma unroll
  for (int m = 0; m < 3; ++m)
    #pragma unroll
    for (int cg = 0; cg < NCOG; ++cg) {
      floatx4 a = acc[m][cg];
      redf[((w * 3 + m) * NCOG + cg) * 64 + l] = make_float4(a[0], a[1], a[2], a[3]);
    }
  __syncthreads();
  const int ryt = (NCOG == 2) ? (w >> 1) : w;
  const int rcg = (NCOG == 2) ? (w & 1) : 0;
  const bool isred = w < 2 * NCOG;
  if (isred) {
    const float bvv = bias[rcg * 16 + col];
    float rs1 = 0.f, rs2 = 0.f;
    #pragma unroll
    for (int m = 0; m < 3; ++m) {
      float vs[4] = {0.f, 0.f, 0.f, 0.f};
      #pragma unroll
      for (int k = 0; k < 2; ++k) {            // reduce the 2 vtap slices
        float4 vv = redf[((((ryt * 2 + k) * 3) + m) * NCOG + rcg) * 64 + l];
        vs[0] += vv.x; vs[1] += vv.y; vs[2] += vv.z; vs[3] += vv.w;
      }
      const int yy = y0q + ryt * 3 + m;
      const int vbase = ((t * 24 + x) * 24 + yy) * 12;
      #pragma unroll
      for (int i = 0; i < 4; ++i) {
        int pz = g * 4 + i;
        float val = vs[i] + bvv;
        if ((unsigned)(pz - 2) < 12u) {
          convout[(size_t)(vbase + pz - 2) * COUT + rcg * 16 + col] = f2bf(val);
          rs1 += val;
          rs2 = fmaf(val, val, rs2);
        }
      }
    }
    rs1 += __shfl_xor(rs1, 16); rs1 += __shfl_xor(rs1, 32);
    rs2 += __shfl_xor(rs2, 16); rs2 += __shfl_xor(rs2, 32);
    if (l < 16) {
      size_t pb = ((size_t)(bid * 2 + ryt) * COUT + rcg * 16 + l) * 2;
      part[pb] = rs1; part[pb + 1] = rs2;
    }
  }
}

// ---------------- BN stats: reduce 1152 block-partials (1024 thr) ---------
template<int C>
__global__ __launch_bounds__(1024) void bn_stats2(
    const float* __restrict__ part, const float* __restrict__ gam,
    const float* __restrict__ bet, float* __restrict__ stats) {
  constexpr int NS = 1024 / C;
  int tid = threadIdx.x;
  int c = tid & (C - 1);
  int sl = tid / C;
  float S = 0.f, S2 = 0.f;
  for (int b = sl; b < 1152; b += NS) {
    S  += part[((size_t)b * C + c) * 2];
    S2 += part[((size_t)b * C + c) * 2 + 1];
  }
  __shared__ float sh[1024][2];
  sh[tid][0] = S; sh[tid][1] = S2;
  __syncthreads();
  if (tid < C) {
    float s = 0.f, s2 = 0.f;
    #pragma unroll
    for (int k = 0; k < NS; ++k) { s += sh[k * C + tid][0]; s2 += sh[k * C + tid][1]; }
    float mean = s * (1.f / VOL);
    float var = fmaxf(s2 * (1.f / VOL) - mean * mean, 0.f);
    float sc = gam[tid] * rsqrtf(var + EPSV);
    stats[2 * tid] = sc;
    stats[2 * tid + 1] = fmaf(-mean, sc, bet[tid]);
  }
}

// ---------------- BN apply + LeakyReLU -> padded bf16 act halves ----------
template<int C>
__global__ __launch_bounds__(256) void bn_apply(
    const unsigned short* __restrict__ convb, const float* __restrict__ stats,
    unsigned short* __restrict__ act) {
  int i = blockIdx.x * 256 + threadIdx.x;
  size_t e = (size_t)i * 8;
  int v = (int)(e / C);
  int cb = (int)(e & (C - 1));
  int z = v % 12, y = (v / 12) % 24, xx = (v / 288) % 24, t = v / 6912;
  size_t pv = (size_t)((t * 24 + xx) * 28 + y + 2) * 16 + z + 2;
  size_t pa = (C == 16) ? (pv * 16 + cb)
                        : ((size_t)(cb >> 4) * HALFELEMS + pv * 16 + (cb & 15));
  short8 in = *reinterpret_cast<const short8*>(convb + e);
  short8 o;
  #pragma unroll
  for (int k = 0; k < 8; ++k) {
    float sc = stats[2 * (cb + k)], sh = stats[2 * (cb + k) + 1];
    float xv = fmaf(bf2f((unsigned short)in[k]), sc, sh);
    xv = fmaxf(xv, SLOPE * xv);
    o[k] = (short)f2bf(xv);
  }
  *reinterpret_cast<short8*>(act + pa) = o;
}

// ---------------- layer3 BN apply + LeakyReLU + projection (fused) --------
__global__ __launch_bounds__(256) void bn_apply_proj(
    const unsigned short* __restrict__ convb, const float* __restrict__ stats,
    const float* __restrict__ wp, const float* __restrict__ bpj,
    float* __restrict__ out) {
  int i = blockIdx.x * 256 + threadIdx.x;     // 2 threads per voxel
  int v = i >> 1;
  int cb = (i & 1) * 8;
  short8 in = *reinterpret_cast<const short8*>(convb + (size_t)v * 16 + cb);
  float s = 0.f;
  #pragma unroll
  for (int k = 0; k < 8; ++k) {
    float sc = stats[2 * (cb + k)], sh = stats[2 * (cb + k) + 1];
    float xv = fmaf(bf2f((unsigned short)in[k]), sc, sh);
    xv = fmaxf(xv, SLOPE * xv);
    s = fmaf(xv, wp[cb + k], s);
  }
  float o = s + __shfl_xor(s, 1);
  if ((i & 1) == 0) out[v] = o + bpj[0];
}

extern "C" void kernel_launch(void* const* d_in, const int* in_sizes, int n_in,
                              void* d_out, int out_size, void* d_ws, size_t ws_size,
                              hipStream_t stream) {
  const float* x      = (const float*)d_in[0];
  const float* w_emb  = (const float*)d_in[1];
  const float* b_emb  = (const float*)d_in[2];
  const float* w1     = (const float*)d_in[3];
  const float* b1     = (const float*)d_in[4];
  const float* g1     = (const float*)d_in[5];
  const float* be1    = (const float*)d_in[6];
  const float* w2     = (const float*)d_in[7];
  const float* b2     = (const float*)d_in[8];
  const float* g2     = (const float*)d_in[9];
  const float* be2    = (const float*)d_in[10];
  const float* w3     = (const float*)d_in[11];
  const float* b3     = (const float*)d_in[12];
  const float* g3     = (const float*)d_in[13];
  const float* be3    = (const float*)d_in[14];
  const float* w_proj = (const float*)d_in[15];
  const float* b_proj = (const float*)d_in[16];

  char* ws = (char*)d_ws;
  unsigned short* ACT   = (unsigned short*)(ws + ACT_B);
  unsigned short* CONVB = (unsigned short*)(ws + CONVB_B);
  short8* WB            = (short8*)(ws + WB_B);
  float* PART           = (float*)(ws + PART_B);
  float* STATS          = (float*)(ws + STATS_B);
  float* out            = (float*)d_out;

  init_all<<<811, 256, 0, stream>>>(x, w_emb, b_emb, w1, w2, w3, ACT, WB);

  // layer 1: 16 -> 16
  conv4d_v17<1, 1><<<576, 256, 0, stream>>>(ACT, WB, b1, CONVB, PART);
  bn_stats2<16><<<1, 1024, 0, stream>>>(PART, g1, be1, STATS);
  bn_apply<16><<<324, 256, 0, stream>>>(CONVB, STATS, ACT);

  // layer 2: 16 -> 32 (writes two ci-half tensors)
  conv4d_v17<1, 2><<<576, 256, 0, stream>>>(ACT, WB + 24000, b2, CONVB, PART);
  bn_stats2<32><<<1, 1024, 0, stream>>>(PART, g2, be2, STATS);
  bn_apply<32><<<648, 256, 0, stream>>>(CONVB, STATS, ACT);

  // layer 3: 32 -> 16 (NH=2 ci-half vtaps), fused BN+proj epilogue
  conv4d_v17<2, 1><<<576, 256, 0, stream>>>(ACT, WB + 72000, b3, CONVB, PART);
  bn_stats2<16><<<1, 1024, 0, stream>>>(PART, g3, be3, STATS);
  bn_apply_proj<<<324, 256, 0, stream>>>(CONVB, STATS, w_proj, b_proj, out);
}

// Round 18
// 138.544 us; speedup vs baseline: 1.2229x; 1.2229x over previous
//
#include <hip/hip_runtime.h>

typedef short short8 __attribute__((ext_vector_type(8)));
typedef float floatx4 __attribute__((ext_vector_type(4)));

#define VOL 41472   // 6*24*24*12
#define EPSV 1e-5f
#define SLOPE 0.1f

// Padded act half-tensors (stride 16 ch): pv(t,x,y,z) = ((t*24+x)*28+y+2)*16+z+2
// half h at ACT + h*HALFELEMS. Halo rows (py 0,1,26,27 / pz 0,1,14,15) zero.
#define HALFBYTES 2064384u
#define HALFELEMS 1032192u
#define ACT_B     256u
#define CONVB_B   4129280u                 // bf16 conv out VOL*32*2 = 2,654,208
#define WB_B      6783488u                 // 120000 short8 = 1.92MB
#define PART_B    8703488u                 // 1152*32*2*4 = 294,912
#define STATS_B   8998400u                 // 512B

__device__ inline unsigned short f2bf(float f) {
  unsigned u = __builtin_bit_cast(unsigned, f);
  unsigned r = u + 0x7fffu + ((u >> 16) & 1u);
  return (unsigned short)(r >> 16);
}
__device__ inline float bf2f(unsigned short h) {
  unsigned u = ((unsigned)h) << 16;
  return __builtin_bit_cast(float, u);
}

// direct global->LDS DMA, 16B per lane. LDS dest = wave-uniform base + lane*16,
// global src is per-lane (guide §5; m97 pattern).
__device__ inline void glds16(const char* g, char* l) {
  __builtin_amdgcn_global_load_lds(
      (const __attribute__((address_space(1))) void*)g,
      (__attribute__((address_space(3))) void*)l, 16, 0, 0);
}

// ---------------- init: halo-zero + embed + wtrans (one kernel) ------------
__global__ __launch_bounds__(256) void init_all(
    const float* __restrict__ x, const float* __restrict__ w_emb,
    const float* __restrict__ b_emb, const float* __restrict__ w1,
    const float* __restrict__ w2, const float* __restrict__ w3,
    unsigned short* __restrict__ act, short8* __restrict__ wb) {
  const int bid = blockIdx.x;
  if (bid < 180) {
    int id = bid * 256 + threadIdx.x;
    if (id < 46080) {
      int half = id / 23040;
      int r0 = id % 23040;
      int colm = r0 / 160;                  // t*24+x
      int r = r0 % 160;
      int py, pz;
      if (r < 64) { int sel = r >> 4; py = (sel < 2) ? sel : sel + 24; pz = r & 15; }
      else { int rr = r - 64; py = 2 + (rr >> 2); int s = rr & 3; pz = (s < 2) ? s : s + 12; }
      size_t pv = ((size_t)colm * 28 + py) * 16 + pz;
      short8 zz = {0,0,0,0,0,0,0,0};
      short8* p = reinterpret_cast<short8*>(act + (size_t)half * HALFELEMS + pv * 16);
      p[0] = zz; p[1] = zz;
    }
  } else if (bid < 342) {
    int v = (bid - 180) * 256 + threadIdx.x;
    const float4* xp = reinterpret_cast<const float4*>(x + (size_t)v * 8);
    float4 x0 = xp[0], x1 = xp[1];
    float xv[8] = {x0.x, x0.y, x0.z, x0.w, x1.x, x1.y, x1.z, x1.w};
    float acc[16];
    #pragma unroll
    for (int h = 0; h < 16; ++h) acc[h] = b_emb[h];
    #pragma unroll
    for (int f = 0; f < 8; ++f)
      #pragma unroll
      for (int h = 0; h < 16; ++h)
        acc[h] = fmaf(xv[f], w_emb[f * 16 + h], acc[h]);
    int z = v % 12, y = (v / 12) % 24, xx = (v / 288) % 24, t = v / 6912;
    size_t pa = ((size_t)((t * 24 + xx) * 28 + y + 2) * 16 + z + 2) * 16;
    short8 o0, o1;
    #pragma unroll
    for (int h = 0; h < 8; ++h) { o0[h] = (short)f2bf(acc[h]); o1[h] = (short)f2bf(acc[8 + h]); }
    short8* op = reinterpret_cast<short8*>(act + pa);
    op[0] = o0; op[1] = o1;
  } else {
    int id = (bid - 342) * 256 + threadIdx.x;
    if (id >= 120000) return;
    int lane = id & 63;
    int n = lane & 15, g = lane >> 4;
    int dzb = g >> 1, cib = (g & 1) * 8;
    short8 out;
    if (id < 24000) {
      int q6 = id >> 6;
      int p = q6 % 3, q = q6 / 3;
      int dz = 2 * p + dzb;
      #pragma unroll
      for (int j = 0; j < 8; ++j)
        out[j] = (short)((dz < 5) ? f2bf(w1[((size_t)n * 16 + cib + j) * 625 + q * 5 + dz]) : 0);
    } else if (id < 72000) {
      int q6 = (id - 24000) >> 6;
      int cg = q6 & 1, p = (q6 >> 1) % 3, q = q6 / 6;
      int dz = 2 * p + dzb;
      int co = cg * 16 + n;
      #pragma unroll
      for (int j = 0; j < 8; ++j)
        out[j] = (short)((dz < 5) ? f2bf(w2[((size_t)co * 16 + cib + j) * 625 + q * 5 + dz]) : 0);
    } else {
      int q6 = (id - 72000) >> 6;
      int p = q6 % 3, Q = q6 / 3;
      int h = Q & 1, q125 = Q >> 1;
      int dz = 2 * p + dzb;
      #pragma unroll
      for (int j = 0; j < 8; ++j)
        out[j] = (short)((dz < 5) ? f2bf(w3[((size_t)n * 32 + h * 16 + cib + j) * 625 + q125 * 5 + dz]) : 0);
    }
    wb[id] = out;
  }
}

// ---------------- conv4d v18: v15 core + global_load_lds staging ----------
// 576 blocks (t,x,yq=6rows) x 8 waves (2 y-triples x 4 vtap-slices), 512 thr.
// 32B-stride dbuf slabs, ONE barrier/step, no swizzle. Staging now uses
// direct global->LDS DMA (no VGPR round-trip, no ds_writes on the LDS pipe;
// loads stay in flight across the whole compute phase, drained by the
// pre-barrier vmcnt). Guard rows 0,1 + slack 162..164 zeroed (R11 lesson).
template<int NH, int NCOG>
__global__ __launch_bounds__(512, 4) void conv4d_v18(
    const unsigned short* __restrict__ act, const short8* __restrict__ wb,
    const float* __restrict__ bias, unsigned short* __restrict__ convout,
    float* __restrict__ part) {
  constexpr int COUT = NCOG * 16;
  constexpr int BUFSZ = 165 * 32;               // 2 guard + 160 data + 3 slack
  constexpr int DYST = NH * 3 * NCOG * 64;      // short8 units per dy step
  constexpr int OVER = 8 * 3 * NCOG * 64 * 16;  // epilogue overlay bytes
  constexpr int SLAB8 = 8 * BUFSZ;              // 42240
  constexpr int LDSZ = (OVER > SLAB8) ? OVER : SLAB8;

  __shared__ __align__(16) char lds[LDSZ];
  __shared__ int vlist[52];

  const int tid = threadIdx.x;
  const int l = tid & 63;
  const int w = tid >> 6;
  const int ks = w & 3;                        // vtap slice
  const int yt = w >> 2;                       // y-triple
  const int col = l & 15, g = l >> 4;
  const int bid = blockIdx.x;                  // no swizzle (R14 lesson)
  const int yq = bid & 3;
  const int x = (bid >> 2) % 24;
  const int t = bid / 96;
  const int y0q = yq * 6;

  // zero guard rows {0,1} + slack rows {162,163,164} of all 8 buffers
  for (int i = tid; i < 320; i += 512) {
    int b = i / 40, j = i % 40;
    int row = (j < 16) ? (j >> 3) : (162 + ((j - 16) >> 3));
    ((int*)(lds + b * BUFSZ + row * 32))[j & 7] = 0;
  }
  // wave-parallel vlist build (wave 0)
  if (tid < 64) {
    int q = tid;
    bool val = false; int pi = 0;
    if (q < 25) {
      int ti = t + q / 5 - 2, xi = x + q % 5 - 2;
      val = ((unsigned)ti < 6u) && ((unsigned)xi < 24u);
      pi = ti * 24 + xi;
    }
    unsigned long long mask = __ballot(val);
    int pos = __popcll(mask & ((1ull << tid) - 1ull));
    if (val)
      #pragma unroll
      for (int h = 0; h < NH; ++h)
        vlist[pos * NH + h] = (pi << 16) | (q * 5 * NH + h);
    if (tid == 0) vlist[51] = __popcll(mask) * NH;
  }
  __syncthreads();
  const int nv = vlist[51];
  const int lo = (nv * ks) >> 2;
  const int hi = (nv * (ks + 1)) >> 2;
  const int nsteps = (nv + 3) >> 2;

  char* const buf0 = lds + (ks * 2) * BUFSZ;
  char* const buf1 = buf0 + BUFSZ;
  const char* const abase = (const char*)act;

  // A-frag read bases (2-row guard cancels the pz -2 halo offset)
  const char* const arp0 = buf0 + (yt * 48 + col + (g >> 1)) * 32 + (g & 1) * 16;
  const char* const arp1 = buf1 + (yt * 48 + col + (g >> 1)) * 32 + (g & 1) * 16;

  floatx4 acc[3][NCOG];
  #pragma unroll
  for (int m = 0; m < 3; ++m)
    #pragma unroll
    for (int cg = 0; cg < NCOG; ++cg) acc[m][cg] = (floatx4){0.f, 0.f, 0.f, 0.f};

  // staging via global_load_lds: 320 chunks of 16B per slab.
  // wave yt covers chunks {yt*64+l, yt*64+128+l, (yt==0: 256+l)}.
  // LDS dest passed wave-uniform; HW adds lane*16 (matches src layout).
  #define STAGE_GLDS(vt, b_) do {                                              \
    int e_ = vlist[vt];                                                        \
    int pi_ = e_ >> 16, h_ = (NH == 2) ? (e_ & 1) : 0;                         \
    const char* sb_ = abase + (size_t)h_ * HALFBYTES +                         \
        ((size_t)(pi_ * 28 + y0q) * 16) * 32 + yt * 1024 + l * 16;             \
    char* db_ = (b_) + 64 + yt * 1024;                                         \
    glds16(sb_, db_);                                                          \
    glds16(sb_ + 2048, db_ + 2048);                                            \
    if (yt == 0) glds16(sb_ + 4096, db_ + 4096);                               \
  } while (0)

  if (lo < hi) STAGE_GLDS(lo, buf0);

  for (int s = 0; s < nsteps; ++s) {
    __syncthreads();                           // buf[s&1] DMA complete (vmcnt drain)
    if (lo + s + 1 < hi) STAGE_GLDS(lo + s + 1, (s & 1) ? buf0 : buf1);
    if (lo + s < hi) {                         // compute vtap s from buf[s&1]
      const int e = vlist[lo + s];
      const short8* bp = wb + (size_t)(e & 0xFFFF) * (3 * NCOG * 64) + l;
      const char* arp = (s & 1) ? arp1 : arp0;
      short8 W[3][3];
      #pragma unroll
      for (int r = 0; r < 3; ++r)
        #pragma unroll
        for (int p = 0; p < 3; ++p)
          W[r][p] = *(const short8*)(arp + r * 512 + p * 64);
      #pragma unroll
      for (int dy = 0; dy < 5; ++dy) {
        short8 Bf[3][NCOG];
        #pragma unroll
        for (int p = 0; p < 3; ++p)
          #pragma unroll
          for (int cg = 0; cg < NCOG; ++cg)
            Bf[p][cg] = bp[dy * DYST + (p * NCOG + cg) * 64];
        #pragma unroll
        for (int p = 0; p < 3; ++p)
          #pragma unroll
          for (int cg = 0; cg < NCOG; ++cg)
            #pragma unroll
            for (int m = 0; m < 3; ++m)
              acc[m][cg] = __builtin_amdgcn_mfma_f32_16x16x32_bf16(
                  W[(dy + m) % 3][p], Bf[p][cg], acc[m][cg], 0, 0, 0);
        if (dy < 4) {
          #pragma unroll
          for (int p = 0; p < 3; ++p)
            W[dy % 3][p] = *(const short8*)(arp + (dy + 3) * 512 + p * 64);
        }
      }
    }
  }
  #undef STAGE_GLDS

  // ---- epilogue: overlay reduce over slices, bias, bf16, BN partials ------
  float4* redf = (float4*)lds;
  __syncthreads();                             // all waves done with slabs
  #pragma unroll
  for (int m = 0; m < 3; ++m)
    #pragma unroll
    for (int cg = 0; cg < NCOG; ++cg) {
      floatx4 a = acc[m][cg];
      redf[((w * 3 + m) * NCOG + cg) * 64 + l] = make_float4(a[0], a[1], a[2], a[3]);
    }
  __syncthreads();
  const int ryt = (NCOG == 2) ? (w >> 1) : w;
  const int rcg = (NCOG == 2) ? (w & 1) : 0;
  const bool isred = w < 2 * NCOG;
  if (isred) {
    const float bvv = bias[rcg * 16 + col];
    float rs1 = 0.f, rs2 = 0.f;
    #pragma unroll
    for (int m = 0; m < 3; ++m) {
      float vs[4] = {0.f, 0.f, 0.f, 0.f};
      #pragma unroll
      for (int k = 0; k < 4; ++k) {
        float4 vv = redf[(((ryt * 4 + k) * 3 + m) * NCOG + rcg) * 64 + l];
        vs[0] += vv.x; vs[1] += vv.y; vs[2] += vv.z; vs[3] += vv.w;
      }
      const int yy = y0q + ryt * 3 + m;
      const int vbase = ((t * 24 + x) * 24 + yy) * 12;
      #pragma unroll
      for (int i = 0; i < 4; ++i) {
        int pz = g * 4 + i;
        float val = vs[i] + bvv;
        if ((unsigned)(pz - 2) < 12u) {
          convout[(size_t)(vbase + pz - 2) * COUT + rcg * 16 + col] = f2bf(val);
          rs1 += val;
          rs2 = fmaf(val, val, rs2);
        }
      }
    }
    rs1 += __shfl_xor(rs1, 16); rs1 += __shfl_xor(rs1, 32);
    rs2 += __shfl_xor(rs2, 16); rs2 += __shfl_xor(rs2, 32);
    if (l < 16) {
      size_t pb = ((size_t)(bid * 2 + ryt) * COUT + rcg * 16 + l) * 2;
      part[pb] = rs1; part[pb + 1] = rs2;
    }
  }
}

// ---------------- BN stats: reduce 1152 block-partials (1024 thr) ---------
template<int C>
__global__ __launch_bounds__(1024) void bn_stats2(
    const float* __restrict__ part, const float* __restrict__ gam,
    const float* __restrict__ bet, float* __restrict__ stats) {
  constexpr int NS = 1024 / C;
  int tid = threadIdx.x;
  int c = tid & (C - 1);
  int sl = tid / C;
  float S = 0.f, S2 = 0.f;
  for (int b = sl; b < 1152; b += NS) {
    S  += part[((size_t)b * C + c) * 2];
    S2 += part[((size_t)b * C + c) * 2 + 1];
  }
  __shared__ float sh[1024][2];
  sh[tid][0] = S; sh[tid][1] = S2;
  __syncthreads();
  if (tid < C) {
    float s = 0.f, s2 = 0.f;
    #pragma unroll
    for (int k = 0; k < NS; ++k) { s += sh[k * C + tid][0]; s2 += sh[k * C + tid][1]; }
    float mean = s * (1.f / VOL);
    float var = fmaxf(s2 * (1.f / VOL) - mean * mean, 0.f);
    float sc = gam[tid] * rsqrtf(var + EPSV);
    stats[2 * tid] = sc;
    stats[2 * tid + 1] = fmaf(-mean, sc, bet[tid]);
  }
}

// ---------------- BN apply + LeakyReLU -> padded bf16 act halves ----------
template<int C>
__global__ __launch_bounds__(256) void bn_apply(
    const unsigned short* __restrict__ convb, const float* __restrict__ stats,
    unsigned short* __restrict__ act) {
  int i = blockIdx.x * 256 + threadIdx.x;
  size_t e = (size_t)i * 8;
  int v = (int)(e / C);
  int cb = (int)(e & (C - 1));
  int z = v % 12, y = (v / 12) % 24, xx = (v / 288) % 24, t = v / 6912;
  size_t pv = (size_t)((t * 24 + xx) * 28 + y + 2) * 16 + z + 2;
  size_t pa = (C == 16) ? (pv * 16 + cb)
                        : ((size_t)(cb >> 4) * HALFELEMS + pv * 16 + (cb & 15));
  short8 in = *reinterpret_cast<const short8*>(convb + e);
  short8 o;
  #pragma unroll
  for (int k = 0; k < 8; ++k) {
    float sc = stats[2 * (cb + k)], sh = stats[2 * (cb + k) + 1];
    float xv = fmaf(bf2f((unsigned short)in[k]), sc, sh);
    xv = fmaxf(xv, SLOPE * xv);
    o[k] = (short)f2bf(xv);
  }
  *reinterpret_cast<short8*>(act + pa) = o;
}

// ---------------- layer3 BN apply + LeakyReLU + projection (fused) --------
__global__ __launch_bounds__(256) void bn_apply_proj(
    const unsigned short* __restrict__ convb, const float* __restrict__ stats,
    const float* __restrict__ wp, const float* __restrict__ bpj,
    float* __restrict__ out) {
  int i = blockIdx.x * 256 + threadIdx.x;     // 2 threads per voxel
  int v = i >> 1;
  int cb = (i & 1) * 8;
  short8 in = *reinterpret_cast<const short8*>(convb + (size_t)v * 16 + cb);
  float s = 0.f;
  #pragma unroll
  for (int k = 0; k < 8; ++k) {
    float sc = stats[2 * (cb + k)], sh = stats[2 * (cb + k) + 1];
    float xv = fmaf(bf2f((unsigned short)in[k]), sc, sh);
    xv = fmaxf(xv, SLOPE * xv);
    s = fmaf(xv, wp[cb + k], s);
  }
  float o = s + __shfl_xor(s, 1);
  if ((i & 1) == 0) out[v] = o + bpj[0];
}

extern "C" void kernel_launch(void* const* d_in, const int* in_sizes, int n_in,
                              void* d_out, int out_size, void* d_ws, size_t ws_size,
                              hipStream_t stream) {
  const float* x      = (const float*)d_in[0];
  const float* w_emb  = (const float*)d_in[1];
  const float* b_emb  = (const float*)d_in[2];
  const float* w1     = (const float*)d_in[3];
  const float* b1     = (const float*)d_in[4];
  const float* g1     = (const float*)d_in[5];
  const float* be1    = (const float*)d_in[6];
  const float* w2     = (const float*)d_in[7];
  const float* b2     = (const float*)d_in[8];
  const float* g2     = (const float*)d_in[9];
  const float* be2    = (const float*)d_in[10];
  const float* w3     = (const float*)d_in[11];
  const float* b3     = (const float*)d_in[12];
  const float* g3     = (const float*)d_in[13];
  const float* be3    = (const float*)d_in[14];
  const float* w_proj = (const float*)d_in[15];
  const float* b_proj = (const float*)d_in[16];

  char* ws = (char*)d_ws;
  unsigned short* ACT   = (unsigned short*)(ws + ACT_B);
  unsigned short* CONVB = (unsigned short*)(ws + CONVB_B);
  short8* WB            = (short8*)(ws + WB_B);
  float* PART           = (float*)(ws + PART_B);
  float* STATS          = (float*)(ws + STATS_B);
  float* out            = (float*)d_out;

  init_all<<<811, 256, 0, stream>>>(x, w_emb, b_emb, w1, w2, w3, ACT, WB);

  // layer 1: 16 -> 16
  conv4d_v18<1, 1><<<576, 512, 0, stream>>>(ACT, WB, b1, CONVB, PART);
  bn_stats2<16><<<1, 1024, 0, stream>>>(PART, g1, be1, STATS);
  bn_apply<16><<<324, 256, 0, stream>>>(CONVB, STATS, ACT);

  // layer 2: 16 -> 32 (writes two ci-half tensors)
  conv4d_v18<1, 2><<<576, 512, 0, stream>>>(ACT, WB + 24000, b2, CONVB, PART);
  bn_stats2<32><<<1, 1024, 0, stream>>>(PART, g2, be2, STATS);
  bn_apply<32><<<648, 256, 0, stream>>>(CONVB, STATS, ACT);

  // layer 3: 32 -> 16 (NH=2 ci-half vtaps), fused BN+proj epilogue
  conv4d_v18<2, 1><<<576, 512, 0, stream>>>(ACT, WB + 72000, b3, CONVB, PART);
  bn_stats2<16><<<1, 1024, 0, stream>>>(PART, g3, be3, STATS);
  bn_apply_proj<<<324, 256, 0, stream>>>(CONVB, STATS, w_proj, b_proj, out);
}